// Round 16
// baseline (409.049 us; speedup 1.0000x reference)
//
#include <hip/hip_runtime.h>

// MultiHeadAttention fwd, MI355X/gfx950.
// B=2, S=2048, D=1024, H=16, dh=64.
// d_out = [output (2*2048*1024 f32)] ++ [attn_weights = softmax(logits, axis=q) (2*16*2048*2048 f32)]
// R16 = R15 (384.3us) with NT removed from attnw stores (plain dwordx4 through L2).
//       Single-variable A/B: resolves NT-bypass vs L2-aggregation mechanism.

typedef unsigned short u16;
typedef __attribute__((ext_vector_type(8))) short short8;
typedef __attribute__((ext_vector_type(8))) _Float16 half8;
typedef __attribute__((ext_vector_type(4))) float f32x4;

#define SEQ 2048
#define DMODEL 1024
#define NHEAD 16
#define DH 64

__device__ __forceinline__ u16 f2h(float f) {
  _Float16 h = (_Float16)f;
  return __builtin_bit_cast(u16, h);
}

// async global->LDS, 16B per lane; lds pointer must be wave-uniform (HW adds lane*16)
__device__ __forceinline__ void gload16(const void* g, void* l) {
  __builtin_amdgcn_global_load_lds(
      (__attribute__((address_space(1))) void*)const_cast<void*>(g),
      (__attribute__((address_space(3))) void*)l, 16, 0, 0);
}

// ---------------------------------------------------------------- converts
__global__ __launch_bounds__(256) void conv_qkv_k(
    const float* __restrict__ qs, const float* __restrict__ ks,
    const float* __restrict__ vs, u16* __restrict__ xq,
    u16* __restrict__ xk, u16* __restrict__ xv)
{
  int z = blockIdx.y;
  const float* s = (z == 0) ? qs : ((z == 1) ? ks : vs);
  u16* d = (z == 0) ? xq : ((z == 1) ? xk : xv);
  size_t i = ((size_t)blockIdx.x * 256 + threadIdx.x) * 8;
  float4 a = *(const float4*)(s + i);
  float4 b = *(const float4*)(s + i + 4);
  short8 o;
  o[0] = (short)f2h(a.x); o[1] = (short)f2h(a.y);
  o[2] = (short)f2h(a.z); o[3] = (short)f2h(a.w);
  o[4] = (short)f2h(b.x); o[5] = (short)f2h(b.y);
  o[6] = (short)f2h(b.z); o[7] = (short)f2h(b.w);
  *(short8*)(d + i) = o;
}

// W[k][n] f32 -> Wt[n][k] fp16 (so GEMM B-fragments read k-contiguous)
__global__ __launch_bounds__(256) void conv_wt_k(
    const float* __restrict__ w0, const float* __restrict__ w1,
    const float* __restrict__ w2, const float* __restrict__ w3,
    u16* __restrict__ t0, u16* __restrict__ t1,
    u16* __restrict__ t2, u16* __restrict__ t3)
{
  __shared__ u16 tile[64][65];
  int z = blockIdx.z;
  const float* W = (z==0)?w0:((z==1)?w1:((z==2)?w2:w3));
  u16* T = (z==0)?t0:((z==1)?t1:((z==2)?t2:t3));
  int k0 = blockIdx.x*64, n0 = blockIdx.y*64;
  int t = threadIdx.x;
  #pragma unroll
  for (int i=0;i<4;i++) {
    int idx = t + i*256;
    int r = idx >> 4, c4 = (idx & 15)*4;
    float4 f = *(const float4*)(W + (size_t)(k0+r)*DMODEL + n0 + c4);
    tile[r][c4+0] = f2h(f.x); tile[r][c4+1] = f2h(f.y);
    tile[r][c4+2] = f2h(f.z); tile[r][c4+3] = f2h(f.w);
  }
  __syncthreads();
  #pragma unroll
  for (int i=0;i<2;i++) {
    int idx = t + i*256;
    int nr = idx >> 3, c8 = (idx & 7)*8;
    short8 o;
    #pragma unroll
    for (int j=0;j<8;j++) o[j] = (short)tile[c8+j][nr];
    *(short8*)(T + (size_t)(n0+nr)*DMODEL + k0 + c8) = o;
  }
}

// ---------------------------------------------------------------- GEMM
// C[4096 x 1024] = A[4096 x 1024] @ Bt[1024 x 1024]^T + bias
// BM=128 BN=64 BK=64; 256 threads = 4 waves (2x2). 512 blocks (2/CU). ~12us each (R7).
template<int EPI>
__global__ __launch_bounds__(256) void gemm16_k(
    const u16* __restrict__ A, const u16* __restrict__ Bt,
    const float* __restrict__ bias, void* __restrict__ outp)
{
  __shared__ u16 As[128*64];   // 16 KB, chunk-swizzled c^(row&7)
  __shared__ u16 Bs[64*64];    // 8 KB
  const int K = 1024;
  int tid = threadIdx.x, w = tid>>6, l = tid&63;
  int m0 = blockIdx.x*128, n0 = blockIdx.y*64;
  int wm = (w>>1)*64, wn = (w&1)*32;
  const f32x4 z4 = {0.f,0.f,0.f,0.f};
  f32x4 acc[4][2];
  #pragma unroll
  for (int mf=0;mf<4;mf++)
    #pragma unroll
    for (int nf=0;nf<2;nf++) acc[mf][nf] = z4;

  for (int k0=0;k0<K;k0+=64) {
    #pragma unroll
    for (int i=0;i<4;i++) {  // A tile: 1024 chunks of 16B, 4 insts/wave
      int cd = (w*4+i)*64 + l, r = cd>>3, p = cd&7, c = p ^ (r&7);
      gload16(A + (size_t)(m0+r)*K + k0 + c*8, (char*)As + (w*4+i)*1024);
    }
    #pragma unroll
    for (int i=0;i<2;i++) {  // B tile: 512 chunks
      int cd = (w*2+i)*64 + l, r = cd>>3, p = cd&7, c = p ^ (r&7);
      gload16(Bt + (size_t)(n0+r)*K + k0 + c*8, (char*)Bs + (w*2+i)*1024);
    }
    __syncthreads();
    half8 a[4][2], b[2][2];
    #pragma unroll
    for (int mf=0;mf<4;mf++)
      #pragma unroll
      for (int kf=0;kf<2;kf++) {
        int row = wm + mf*16 + (l&15);
        int ch = (kf*4 + (l>>4)) ^ (row&7);
        a[mf][kf] = *(const half8*)&As[row*64 + ch*8];
      }
    #pragma unroll
    for (int nf=0;nf<2;nf++)
      #pragma unroll
      for (int kf=0;kf<2;kf++) {
        int row = wn + nf*16 + (l&15);
        int ch = (kf*4 + (l>>4)) ^ (row&7);
        b[nf][kf] = *(const half8*)&Bs[row*64 + ch*8];
      }
    #pragma unroll
    for (int kf=0;kf<2;kf++)
      #pragma unroll
      for (int mf=0;mf<4;mf++)
        #pragma unroll
        for (int nf=0;nf<2;nf++)
          acc[mf][nf] = __builtin_amdgcn_mfma_f32_16x16x32_f16(
              a[mf][kf], b[nf][kf], acc[mf][nf], 0,0,0);
    __syncthreads();
  }
  #pragma unroll
  for (int mf=0;mf<4;mf++)
    #pragma unroll
    for (int nf=0;nf<2;nf++)
      #pragma unroll
      for (int r=0;r<4;r++) {
        int m = m0 + wm + mf*16 + (l>>4)*4 + r;
        int n = n0 + wn + nf*16 + (l&15);
        float v = acc[mf][nf][r] + bias[n];
        if (EPI == 0) {
          int bb = m >> 11, s = m & 2047, hh = n >> 6, dd = n & 63;
          ((u16*)outp)[((size_t)((bb*16+hh)*2048 + s))*64 + dd] = f2h(v);
        } else if (EPI == 1) {
          int bb = m >> 11, s = m & 2047, hh = n >> 6, dd = n & 63;
          ((u16*)outp)[((size_t)((bb*16+hh)*64 + dd))*2048 + s] = f2h(v);
        } else {
          ((float*)outp)[(size_t)m*DMODEL + n] = v;
        }
      }
}

// ---------------------------------------------------------------- flash attention (R9/R12 version)
// QBLK=64 (4 waves x 16 q-rows), grid (32,32)=1024 wg. KVBLK=128 per kt.
// K/V staged once per block into LDS via global_load_lds (pre-swizzled source),
// fragments via swizzled ds_read_b128. LDS 56KB -> 2 blocks/CU.
__global__ __launch_bounds__(256) void flash_k(
    const u16* __restrict__ Qh, const u16* __restrict__ Kh,
    const u16* __restrict__ Vt, const float* __restrict__ mask,
    u16* __restrict__ Cc, float* __restrict__ colsum)
{
  __shared__ u16 Ks[128*64];      // 16 KB, chunk-swizzle c^(row&7)  (rows=k)
  __shared__ u16 Vs[64*128];      // 16 KB, chunk-swizzle c^(row&15) (rows=d)
  __shared__ u16 Ps[4][16*128];   // per-wave P staging
  __shared__ float colbuf[SEQ];
  int tid = threadIdx.x, w = tid>>6, l = tid&63;
  int lg = l>>4, li = l&15;
  int qb = blockIdx.x, bh = blockIdx.y, b = bh>>4, h = bh&15;
  const u16* Qb = Qh + (size_t)bh*SEQ*DH;
  const u16* Kb = Kh + (size_t)bh*SEQ*DH;
  const u16* Vb = Vt + (size_t)bh*DH*SEQ;
  const float* mrow = mask + (size_t)b*SEQ;
  for (int i=tid;i<SEQ;i+=256) colbuf[i] = 0.f;
  int q0 = qb*64 + w*16;
  half8 qf[2];
  #pragma unroll
  for (int kf=0;kf<2;kf++)
    qf[kf] = *(const half8*)&Qb[(size_t)(q0+li)*DH + kf*32 + lg*8];
  const f32x4 z4 = {0.f,0.f,0.f,0.f};
  f32x4 acc[4];
  float lrow[4];
  #pragma unroll
  for (int df=0;df<4;df++) acc[df] = z4;
  #pragma unroll
  for (int r=0;r<4;r++) lrow[r] = 0.f;
  u16* Pw = &Ps[w][0];
  for (int kt=0;kt<16;kt++) {
    int k0 = kt*128;
    __syncthreads();   // previous tile's LDS reads complete before overwrite
    #pragma unroll
    for (int i=0;i<4;i++) {   // K tile: 1024 chunks of 16B
      int cd = (w*4+i)*64 + l, r = cd>>3, p = cd&7, c = p ^ (r&7);
      gload16(Kb + (size_t)(k0+r)*DH + c*8, (char*)Ks + (w*4+i)*1024);
    }
    #pragma unroll
    for (int i=0;i<4;i++) {   // V tile: 1024 chunks of 16B
      int cd = (w*4+i)*64 + l, r = cd>>4, p = cd&15, c = p ^ (r&15);
      gload16(Vb + (size_t)r*SEQ + k0 + c*8, (char*)Vs + (w*4+i)*1024);
    }
    __syncthreads();   // vmcnt drained before barrier -> tiles ready
    f32x4 s[8];
    #pragma unroll
    for (int nf=0;nf<8;nf++) s[nf] = z4;
    #pragma unroll
    for (int nf=0;nf<8;nf++) {
      int row = nf*16 + li;
      half8 kb0 = *(const half8*)&Ks[row*64 + ((lg    ) ^ (row&7))*8];
      half8 kb1 = *(const half8*)&Ks[row*64 + ((4 + lg) ^ (row&7))*8];
      s[nf] = __builtin_amdgcn_mfma_f32_16x16x32_f16(qf[0], kb0, s[nf],0,0,0);
      s[nf] = __builtin_amdgcn_mfma_f32_16x16x32_f16(qf[1], kb1, s[nf],0,0,0);
    }
    float mv[8], cp[8];
    #pragma unroll
    for (int nf=0;nf<8;nf++) {
      mv[nf] = mrow[k0 + nf*16 + li] * (-1e9f);
      cp[nf] = 0.f;
    }
    #pragma unroll
    for (int nf=0;nf<8;nf++) {
      f32x4 p;
      #pragma unroll
      for (int r=0;r<4;r++) {
        float e = __expf(s[nf][r]*0.125f + mv[nf]);
        e = fminf(e, 60000.f);   // fp16-range insurance
        p[r] = e;
        lrow[r] += e;
        cp[nf] += e;
      }
      s[nf] = p;
    }
    #pragma unroll
    for (int nf=0;nf<8;nf++) {     // column partials -> LDS
      float vsum = cp[nf];
      vsum += __shfl_xor(vsum, 16);
      vsum += __shfl_xor(vsum, 32);
      if (lg == 0) atomicAdd(&colbuf[k0 + nf*16 + li], vsum);
    }
    // P (row=lg*4+r, col=li within nf) -> LDS transposed for PV A-operand
    #pragma unroll
    for (int nf=0;nf<8;nf++) {
      int kc = nf*16 + li;
      #pragma unroll
      for (int r=0;r<4;r++) {
        int row = lg*4 + r;
        int ch = (kc>>3) ^ row;
        Pw[row*128 + ch*8 + (kc&7)] = f2h(s[nf][r]);
      }
    }
    #pragma unroll
    for (int ks=0;ks<4;ks++) {
      half8 pa;
      {
        int row = li;
        int ch = (ks*4 + lg) ^ row;
        pa = *(const half8*)&Pw[row*128 + ch*8];
      }
      #pragma unroll
      for (int df=0;df<4;df++) {
        int vrow = df*16 + li;
        half8 vb = *(const half8*)&Vs[vrow*128 + ((ks*4 + lg) ^ (vrow&15))*8];
        acc[df] = __builtin_amdgcn_mfma_f32_16x16x32_f16(pa, vb, acc[df],0,0,0);
      }
    }
  }
  #pragma unroll
  for (int r=0;r<4;r++) {        // finalize row sums over the 16 col-lanes
    float vsum = lrow[r];
    vsum += __shfl_xor(vsum, 1);
    vsum += __shfl_xor(vsum, 2);
    vsum += __shfl_xor(vsum, 4);
    vsum += __shfl_xor(vsum, 8);
    lrow[r] = 1.0f / vsum;
  }
  #pragma unroll
  for (int df=0;df<4;df++)
    #pragma unroll
    for (int r=0;r<4;r++) {
      int qrow = q0 + lg*4 + r;
      int col = h*64 + df*16 + li;
      Cc[(size_t)(b*SEQ + qrow)*DMODEL + col] = f2h(acc[df][r] * lrow[r]);
    }
  __syncthreads();
  for (int i=tid;i<SEQ;i+=256) atomicAdd(&colsum[(size_t)bh*SEQ + i], colbuf[i]);
}

// ---------------------------------------------------------------- attn_weights write pass
// Per-wave LDS repack (32x64 f32 tile, stride-68 pad) -> plain dwordx4 stores
// through L2 (R16 A/B: NT removed). Values bit-identical to R12/R15.
__global__ __launch_bounds__(256) void attnw_k(
    const u16* __restrict__ Qh, const u16* __restrict__ Kh,
    const float* __restrict__ mask, const float* __restrict__ colsum,
    float* __restrict__ outw)
{
  __shared__ float Ts[4][32*68];   // 34 KB: per-wave private repack tile
  int tid = threadIdx.x, w = tid>>6, l = tid&63;
  int lg = l>>4, li = l&15;
  int qb = blockIdx.x, bh = blockIdx.y, b = bh>>4;
  int kseg = blockIdx.z;
  const u16* Qb = Qh + (size_t)bh*SEQ*DH;
  const u16* Kb = Kh + (size_t)bh*SEQ*DH;
  const float* mrow = mask + (size_t)b*SEQ;
  const float* csrow = colsum + (size_t)bh*SEQ;
  float* obase = outw + (size_t)bh*SEQ*SEQ;
  int q0 = qb*128 + w*32;
  half8 qf[2][2];
  #pragma unroll
  for (int mf=0;mf<2;mf++)
    #pragma unroll
    for (int kf=0;kf<2;kf++)
      qf[mf][kf] = *(const half8*)&Qb[(size_t)(q0+mf*16+li)*DH + kf*32 + lg*8];
  const f32x4 z4 = {0.f,0.f,0.f,0.f};
  const float UNIF = 4.8828125e-4f;   // 1/2048
  float* Tw = &Ts[w][0];
  for (int kt=kseg*2;kt<kseg*2+2;kt++) {
    int k0 = kt*128;
    f32x4 s[2][8];
    #pragma unroll
    for (int mf=0;mf<2;mf++)
      #pragma unroll
      for (int nf=0;nf<8;nf++) s[mf][nf] = z4;
    #pragma unroll
    for (int nf=0;nf<8;nf++) {
      const u16* kr = &Kb[(size_t)(k0+nf*16+li)*DH + lg*8];
      half8 kb0 = *(const half8*)kr;
      half8 kb1 = *(const half8*)(kr + 32);
      #pragma unroll
      for (int mf=0;mf<2;mf++) {
        s[mf][nf] = __builtin_amdgcn_mfma_f32_16x16x32_f16(qf[mf][0], kb0, s[mf][nf],0,0,0);
        s[mf][nf] = __builtin_amdgcn_mfma_f32_16x16x32_f16(qf[mf][1], kb1, s[mf][nf],0,0,0);
      }
    }
    float rc[8];
    #pragma unroll
    for (int nf=0;nf<8;nf++) {
      int kk = k0 + nf*16 + li;
      rc[nf] = (mrow[kk] != 0.f) ? -1.f : 1.0f/csrow[kk];
    }
    // two passes over k-halves: repack 32x64 through LDS, then dwordx4 stores
    #pragma unroll
    for (int p=0;p<2;p++) {
      #pragma unroll
      for (int nf4=0;nf4<4;nf4++) {
        int nf = 4*p + nf4;
        #pragma unroll
        for (int mf=0;mf<2;mf++)
          #pragma unroll
          for (int r=0;r<4;r++) {
            float val = (rc[nf] < 0.f) ? UNIF
                                       : __expf(s[mf][nf][r]*0.125f)*rc[nf];
            Tw[(mf*16 + lg*4 + r)*68 + nf4*16 + li] = val;
          }
      }
      // wave-private tile: same-wave ds ordering (lgkmcnt) suffices, no barrier
      #pragma unroll
      for (int r4=0;r4<8;r4++) {
        int row = 4*r4 + lg;               // 4 q-rows per inst, 16 lanes x 16B each
        f32x4 v = *(const f32x4*)&Tw[row*68 + 4*li];
        *(f32x4*)(obase + (size_t)(q0+row)*SEQ + k0 + 64*p + 4*li) = v;
      }
    }
  }
}

// ---------------------------------------------------------------- launch
extern "C" void kernel_launch(void* const* d_in, const int* in_sizes, int n_in,
                              void* d_out, int out_size, void* d_ws, size_t ws_size,
                              hipStream_t stream) {
  (void)in_sizes; (void)n_in; (void)out_size; (void)ws_size;
  const float* v_in = (const float*)d_in[0];
  const float* k_in = (const float*)d_in[1];
  const float* q_in = (const float*)d_in[2];
  const float* mask = (const float*)d_in[3];
  const float* wq_w = (const float*)d_in[5];
  const float* wq_b = (const float*)d_in[6];
  const float* wk_w = (const float*)d_in[7];
  const float* wk_b = (const float*)d_in[8];
  const float* wv_w = (const float*)d_in[9];
  const float* wv_b = (const float*)d_in[10];
  const float* wo_w = (const float*)d_in[11];
  const float* wo_b = (const float*)d_in[12];

  char* ws = (char*)d_ws;
  const size_t MB = 1024*1024;
  u16* xq  = (u16*)(ws);             // 8 MB each
  u16* xk  = (u16*)(ws + 8*MB);
  u16* xv  = (u16*)(ws + 16*MB);
  u16* wqt = (u16*)(ws + 24*MB);     // 2 MB each
  u16* wkt = (u16*)(ws + 26*MB);
  u16* wvt = (u16*)(ws + 28*MB);
  u16* wot = (u16*)(ws + 30*MB);
  u16* qh  = (u16*)(ws + 32*MB);     // 8 MB each
  u16* kh  = (u16*)(ws + 40*MB);
  u16* vt  = (u16*)(ws + 48*MB);
  u16* cc  = (u16*)(ws + 56*MB);
  float* colsum = (float*)(ws + 64*MB);  // 256 KB

  float* out0 = (float*)d_out;                       // (2,2048,1024)
  float* outw = out0 + (size_t)2*SEQ*DMODEL;         // (2,16,2048,2048)

  (void)hipMemsetAsync(colsum, 0, (size_t)32*SEQ*sizeof(float), stream);
  conv_qkv_k<<<dim3(2048,3), 256, 0, stream>>>(q_in, k_in, v_in, xq, xk, xv);
  conv_wt_k<<<dim3(16,16,4), 256, 0, stream>>>(wq_w, wk_w, wv_w, wo_w, wqt, wkt, wvt, wot);
  gemm16_k<0><<<dim3(32,16), 256, 0, stream>>>(xq, wqt, wq_b, qh);
  gemm16_k<0><<<dim3(32,16), 256, 0, stream>>>(xk, wkt, wk_b, kh);
  gemm16_k<1><<<dim3(32,16), 256, 0, stream>>>(xv, wvt, wv_b, vt);
  flash_k<<<dim3(32,32), 256, 0, stream>>>(qh, kh, vt, mask, cc, colsum);
  attnw_k<<<dim3(16,32,8), 256, 0, stream>>>(qh, kh, mask, colsum, outw);
  gemm16_k<2><<<dim3(32,16), 256, 0, stream>>>(cc, wot, wo_b, out0);
}

// Round 17
// 391.404 us; speedup vs baseline: 1.0451x; 1.0451x over previous
//
#include <hip/hip_runtime.h>

// MultiHeadAttention fwd, MI355X/gfx950.
// B=2, S=2048, D=1024, H=16, dh=64.
// d_out = [output (2*2048*1024 f32)] ++ [attn_weights = softmax(logits, axis=q) (2*16*2048*2048 f32)]
// R17 = R15 base (384.3us best); flash rebuilt as T3/T4 counted-vmcnt pipeline:
//       KVBLK=64 dbuf (R11's verified math), raw s_barrier + s_waitcnt vmcnt(4),
//       mask pre-staged to LDS flags (compute issues zero VMEM). 52KB -> 3 blocks/CU.

typedef unsigned short u16;
typedef __attribute__((ext_vector_type(8))) short short8;
typedef __attribute__((ext_vector_type(8))) _Float16 half8;
typedef __attribute__((ext_vector_type(4))) float f32x4;

#define SEQ 2048
#define DMODEL 1024
#define NHEAD 16
#define DH 64

__device__ __forceinline__ u16 f2h(float f) {
  _Float16 h = (_Float16)f;
  return __builtin_bit_cast(u16, h);
}

// async global->LDS, 16B per lane; lds pointer must be wave-uniform (HW adds lane*16)
__device__ __forceinline__ void gload16(const void* g, void* l) {
  __builtin_amdgcn_global_load_lds(
      (__attribute__((address_space(1))) void*)const_cast<void*>(g),
      (__attribute__((address_space(3))) void*)l, 16, 0, 0);
}

// ---------------------------------------------------------------- converts
__global__ __launch_bounds__(256) void conv_qkv_k(
    const float* __restrict__ qs, const float* __restrict__ ks,
    const float* __restrict__ vs, u16* __restrict__ xq,
    u16* __restrict__ xk, u16* __restrict__ xv)
{
  int z = blockIdx.y;
  const float* s = (z == 0) ? qs : ((z == 1) ? ks : vs);
  u16* d = (z == 0) ? xq : ((z == 1) ? xk : xv);
  size_t i = ((size_t)blockIdx.x * 256 + threadIdx.x) * 8;
  float4 a = *(const float4*)(s + i);
  float4 b = *(const float4*)(s + i + 4);
  short8 o;
  o[0] = (short)f2h(a.x); o[1] = (short)f2h(a.y);
  o[2] = (short)f2h(a.z); o[3] = (short)f2h(a.w);
  o[4] = (short)f2h(b.x); o[5] = (short)f2h(b.y);
  o[6] = (short)f2h(b.z); o[7] = (short)f2h(b.w);
  *(short8*)(d + i) = o;
}

// W[k][n] f32 -> Wt[n][k] fp16 (so GEMM B-fragments read k-contiguous)
__global__ __launch_bounds__(256) void conv_wt_k(
    const float* __restrict__ w0, const float* __restrict__ w1,
    const float* __restrict__ w2, const float* __restrict__ w3,
    u16* __restrict__ t0, u16* __restrict__ t1,
    u16* __restrict__ t2, u16* __restrict__ t3)
{
  __shared__ u16 tile[64][65];
  int z = blockIdx.z;
  const float* W = (z==0)?w0:((z==1)?w1:((z==2)?w2:w3));
  u16* T = (z==0)?t0:((z==1)?t1:((z==2)?t2:t3));
  int k0 = blockIdx.x*64, n0 = blockIdx.y*64;
  int t = threadIdx.x;
  #pragma unroll
  for (int i=0;i<4;i++) {
    int idx = t + i*256;
    int r = idx >> 4, c4 = (idx & 15)*4;
    float4 f = *(const float4*)(W + (size_t)(k0+r)*DMODEL + n0 + c4);
    tile[r][c4+0] = f2h(f.x); tile[r][c4+1] = f2h(f.y);
    tile[r][c4+2] = f2h(f.z); tile[r][c4+3] = f2h(f.w);
  }
  __syncthreads();
  #pragma unroll
  for (int i=0;i<2;i++) {
    int idx = t + i*256;
    int nr = idx >> 3, c8 = (idx & 7)*8;
    short8 o;
    #pragma unroll
    for (int j=0;j<8;j++) o[j] = (short)tile[c8+j][nr];
    *(short8*)(T + (size_t)(n0+nr)*DMODEL + k0 + c8) = o;
  }
}

// ---------------------------------------------------------------- GEMM
// C[4096 x 1024] = A[4096 x 1024] @ Bt[1024 x 1024]^T + bias
// BM=128 BN=64 BK=64; 256 threads = 4 waves (2x2). 512 blocks (2/CU). ~12us each (R7).
template<int EPI>
__global__ __launch_bounds__(256) void gemm16_k(
    const u16* __restrict__ A, const u16* __restrict__ Bt,
    const float* __restrict__ bias, void* __restrict__ outp)
{
  __shared__ u16 As[128*64];   // 16 KB, chunk-swizzled c^(row&7)
  __shared__ u16 Bs[64*64];    // 8 KB
  const int K = 1024;
  int tid = threadIdx.x, w = tid>>6, l = tid&63;
  int m0 = blockIdx.x*128, n0 = blockIdx.y*64;
  int wm = (w>>1)*64, wn = (w&1)*32;
  const f32x4 z4 = {0.f,0.f,0.f,0.f};
  f32x4 acc[4][2];
  #pragma unroll
  for (int mf=0;mf<4;mf++)
    #pragma unroll
    for (int nf=0;nf<2;nf++) acc[mf][nf] = z4;

  for (int k0=0;k0<K;k0+=64) {
    #pragma unroll
    for (int i=0;i<4;i++) {  // A tile: 1024 chunks of 16B, 4 insts/wave
      int cd = (w*4+i)*64 + l, r = cd>>3, p = cd&7, c = p ^ (r&7);
      gload16(A + (size_t)(m0+r)*K + k0 + c*8, (char*)As + (w*4+i)*1024);
    }
    #pragma unroll
    for (int i=0;i<2;i++) {  // B tile: 512 chunks
      int cd = (w*2+i)*64 + l, r = cd>>3, p = cd&7, c = p ^ (r&7);
      gload16(Bt + (size_t)(n0+r)*K + k0 + c*8, (char*)Bs + (w*2+i)*1024);
    }
    __syncthreads();
    half8 a[4][2], b[2][2];
    #pragma unroll
    for (int mf=0;mf<4;mf++)
      #pragma unroll
      for (int kf=0;kf<2;kf++) {
        int row = wm + mf*16 + (l&15);
        int ch = (kf*4 + (l>>4)) ^ (row&7);
        a[mf][kf] = *(const half8*)&As[row*64 + ch*8];
      }
    #pragma unroll
    for (int nf=0;nf<2;nf++)
      #pragma unroll
      for (int kf=0;kf<2;kf++) {
        int row = wn + nf*16 + (l&15);
        int ch = (kf*4 + (l>>4)) ^ (row&7);
        b[nf][kf] = *(const half8*)&Bs[row*64 + ch*8];
      }
    #pragma unroll
    for (int kf=0;kf<2;kf++)
      #pragma unroll
      for (int mf=0;mf<4;mf++)
        #pragma unroll
        for (int nf=0;nf<2;nf++)
          acc[mf][nf] = __builtin_amdgcn_mfma_f32_16x16x32_f16(
              a[mf][kf], b[nf][kf], acc[mf][nf], 0,0,0);
    __syncthreads();
  }
  #pragma unroll
  for (int mf=0;mf<4;mf++)
    #pragma unroll
    for (int nf=0;nf<2;nf++)
      #pragma unroll
      for (int r=0;r<4;r++) {
        int m = m0 + wm + mf*16 + (l>>4)*4 + r;
        int n = n0 + wn + nf*16 + (l&15);
        float v = acc[mf][nf][r] + bias[n];
        if (EPI == 0) {
          int bb = m >> 11, s = m & 2047, hh = n >> 6, dd = n & 63;
          ((u16*)outp)[((size_t)((bb*16+hh)*2048 + s))*64 + dd] = f2h(v);
        } else if (EPI == 1) {
          int bb = m >> 11, s = m & 2047, hh = n >> 6, dd = n & 63;
          ((u16*)outp)[((size_t)((bb*16+hh)*64 + dd))*2048 + s] = f2h(v);
        } else {
          ((float*)outp)[(size_t)m*DMODEL + n] = v;
        }
      }
}

// ---------------------------------------------------------------- flash attention
// QBLK=64 (4 waves x 16 q-rows), grid (32,32)=1024 wg. KVBLK=64, 32 kt steps.
// T3/T4 pipeline: K/V double-buffered; stage(kt+1) issued, then s_waitcnt vmcnt(4)
// (previous tile's loads retired, new 4 stay in flight across compute), raw s_barrier.
// Mask pre-staged to LDS flags -> compute issues ZERO VMEM ops (vmcnt count exact).
// LDS: 16K(Ks)+16K(Vs)+8K(Ps)+8K(colbuf)+4K(mflag) = 52KB -> 3 blocks/CU.
__global__ __launch_bounds__(256) void flash_k(
    const u16* __restrict__ Qh, const u16* __restrict__ Kh,
    const u16* __restrict__ Vt, const float* __restrict__ mask,
    u16* __restrict__ Cc, float* __restrict__ colsum)
{
  __shared__ u16 Ks[2][64*64];    // rows=k-local, swizzle c^(row&7)
  __shared__ u16 Vs[2][64*64];    // rows=d,       swizzle c^(row&7)
  __shared__ u16 Ps[4][16*64];    // per-wave P, swizzle (kc>>3)^(row&7)
  __shared__ float colbuf[SEQ];
  __shared__ u16 mflag[SEQ];
  int tid = threadIdx.x, w = tid>>6, l = tid&63;
  int lg = l>>4, li = l&15;
  int qb = blockIdx.x, bh = blockIdx.y, b = bh>>4, h = bh&15;
  const u16* Qb = Qh + (size_t)bh*SEQ*DH;
  const u16* Kb = Kh + (size_t)bh*SEQ*DH;
  const u16* Vb = Vt + (size_t)bh*DH*SEQ;
  const float* mrow = mask + (size_t)b*SEQ;

  // stage(buf, kt): K tile 64x64 (8KB, 512 chunks) + V tile 64x64 — 2+2 insts/wave
  auto stage = [&](int buf, int kt) {
    int k0 = kt*64;
    #pragma unroll
    for (int i=0;i<2;i++) {
      int cd = (w*2+i)*64 + l, r = cd>>3, p = cd&7, c = p ^ (r&7);
      gload16(Kb + (size_t)(k0+r)*DH + c*8, (char*)&Ks[buf][0] + (w*2+i)*1024);
    }
    #pragma unroll
    for (int i=0;i<2;i++) {
      int cd = (w*2+i)*64 + l, r = cd>>3, p = cd&7, c = p ^ (r&7);
      gload16(Vb + (size_t)r*SEQ + k0 + c*8, (char*)&Vs[buf][0] + (w*2+i)*1024);
    }
  };

  stage(0, 0);                       // prologue staging (drained by __syncthreads below)
  for (int i=tid;i<SEQ;i+=256) {     // mask flags + colsum accumulator init
    colbuf[i] = 0.f;
    mflag[i] = (mrow[i] != 0.f) ? 1 : 0;
  }
  int q0 = qb*64 + w*16;
  half8 qf[2];
  #pragma unroll
  for (int kf=0;kf<2;kf++)
    qf[kf] = *(const half8*)&Qb[(size_t)(q0+li)*DH + kf*32 + lg*8];
  const f32x4 z4 = {0.f,0.f,0.f,0.f};
  f32x4 acc[4];
  float lrow[4];
  #pragma unroll
  for (int df=0;df<4;df++) acc[df] = z4;
  #pragma unroll
  for (int r=0;r<4;r++) lrow[r] = 0.f;
  u16* Pw = &Ps[w][0];
  __syncthreads();   // full drain once: buf0 + mflag + colbuf ready

  for (int kt=0;kt<32;kt++) {
    int cur = kt & 1;
    int k0 = kt*64;
    if (kt < 31) {
      stage(cur^1, kt+1);            // 4 loads into the buffer computed at kt-1
      asm volatile("s_waitcnt vmcnt(4)" ::: "memory");   // prev stage retired; new 4 in flight
    } else {
      asm volatile("s_waitcnt vmcnt(0)" ::: "memory");
    }
    __builtin_amdgcn_sched_barrier(0);
    __builtin_amdgcn_s_barrier();    // all waves' cur-staging landed
    __builtin_amdgcn_sched_barrier(0);

    f32x4 s[4];
    #pragma unroll
    for (int nf=0;nf<4;nf++) s[nf] = z4;
    #pragma unroll
    for (int nf=0;nf<4;nf++) {
      int row = nf*16 + li;
      half8 kb0 = *(const half8*)&Ks[cur][row*64 + ((lg    ) ^ (row&7))*8];
      half8 kb1 = *(const half8*)&Ks[cur][row*64 + ((4 + lg) ^ (row&7))*8];
      s[nf] = __builtin_amdgcn_mfma_f32_16x16x32_f16(qf[0], kb0, s[nf],0,0,0);
      s[nf] = __builtin_amdgcn_mfma_f32_16x16x32_f16(qf[1], kb1, s[nf],0,0,0);
    }
    float mv[4], cp[4];
    #pragma unroll
    for (int nf=0;nf<4;nf++) {
      mv[nf] = mflag[k0 + nf*16 + li] ? -1e9f : 0.f;   // == mrow*(-1e9), mask in {0,1}
      cp[nf] = 0.f;
    }
    #pragma unroll
    for (int nf=0;nf<4;nf++) {
      f32x4 p;
      #pragma unroll
      for (int r=0;r<4;r++) {
        float e = __expf(s[nf][r]*0.125f + mv[nf]);
        e = fminf(e, 60000.f);   // fp16-range insurance
        p[r] = e;
        lrow[r] += e;
        cp[nf] += e;
      }
      s[nf] = p;
    }
    #pragma unroll
    for (int nf=0;nf<4;nf++) {     // column partials -> LDS
      float vsum = cp[nf];
      vsum += __shfl_xor(vsum, 16);
      vsum += __shfl_xor(vsum, 32);
      if (lg == 0) atomicAdd(&colbuf[k0 + nf*16 + li], vsum);
    }
    // P (row=lg*4+r, col kc=nf*16+li local to 64) -> LDS for PV A-operand
    #pragma unroll
    for (int nf=0;nf<4;nf++) {
      int kc = nf*16 + li;
      #pragma unroll
      for (int r=0;r<4;r++) {
        int row = lg*4 + r;
        int ch = (kc>>3) ^ (row&7);
        Pw[row*64 + ch*8 + (kc&7)] = f2h(s[nf][r]);
      }
    }
    #pragma unroll
    for (int ks=0;ks<2;ks++) {
      half8 pa;
      {
        int row = li;
        int ch = (ks*4 + lg) ^ (row&7);
        pa = *(const half8*)&Pw[row*64 + ch*8];
      }
      #pragma unroll
      for (int df=0;df<4;df++) {
        int vrow = df*16 + li;
        half8 vb = *(const half8*)&Vs[cur][vrow*64 + ((ks*4 + lg) ^ (vrow&7))*8];
        acc[df] = __builtin_amdgcn_mfma_f32_16x16x32_f16(pa, vb, acc[df],0,0,0);
      }
    }
    __builtin_amdgcn_sched_barrier(0);
    __builtin_amdgcn_s_barrier();    // all waves done reading cur before it's restaged
  }
  __syncthreads();   // full drain: colbuf atomics visible for the final pass
  #pragma unroll
  for (int r=0;r<4;r++) {        // finalize row sums over the 16 col-lanes
    float vsum = lrow[r];
    vsum += __shfl_xor(vsum, 1);
    vsum += __shfl_xor(vsum, 2);
    vsum += __shfl_xor(vsum, 4);
    vsum += __shfl_xor(vsum, 8);
    lrow[r] = 1.0f / vsum;
  }
  #pragma unroll
  for (int df=0;df<4;df++)
    #pragma unroll
    for (int r=0;r<4;r++) {
      int qrow = q0 + lg*4 + r;
      int col = h*64 + df*16 + li;
      Cc[(size_t)(b*SEQ + qrow)*DMODEL + col] = f2h(acc[df][r] * lrow[r]);
    }
  for (int i=tid;i<SEQ;i+=256) atomicAdd(&colsum[(size_t)bh*SEQ + i], colbuf[i]);
}

// ---------------------------------------------------------------- attn_weights write pass
// Per-wave LDS repack (32x64 f32 tile, stride-68 pad) -> NT dwordx4 stores (R15 best).
__global__ __launch_bounds__(256) void attnw_k(
    const u16* __restrict__ Qh, const u16* __restrict__ Kh,
    const float* __restrict__ mask, const float* __restrict__ colsum,
    float* __restrict__ outw)
{
  __shared__ float Ts[4][32*68];   // 34 KB: per-wave private repack tile
  int tid = threadIdx.x, w = tid>>6, l = tid&63;
  int lg = l>>4, li = l&15;
  int qb = blockIdx.x, bh = blockIdx.y, b = bh>>4;
  int kseg = blockIdx.z;
  const u16* Qb = Qh + (size_t)bh*SEQ*DH;
  const u16* Kb = Kh + (size_t)bh*SEQ*DH;
  const float* mrow = mask + (size_t)b*SEQ;
  const float* csrow = colsum + (size_t)bh*SEQ;
  float* obase = outw + (size_t)bh*SEQ*SEQ;
  int q0 = qb*128 + w*32;
  half8 qf[2][2];
  #pragma unroll
  for (int mf=0;mf<2;mf++)
    #pragma unroll
    for (int kf=0;kf<2;kf++)
      qf[mf][kf] = *(const half8*)&Qb[(size_t)(q0+mf*16+li)*DH + kf*32 + lg*8];
  const f32x4 z4 = {0.f,0.f,0.f,0.f};
  const float UNIF = 4.8828125e-4f;   // 1/2048
  float* Tw = &Ts[w][0];
  for (int kt=kseg*2;kt<kseg*2+2;kt++) {
    int k0 = kt*128;
    f32x4 s[2][8];
    #pragma unroll
    for (int mf=0;mf<2;mf++)
      #pragma unroll
      for (int nf=0;nf<8;nf++) s[mf][nf] = z4;
    #pragma unroll
    for (int nf=0;nf<8;nf++) {
      const u16* kr = &Kb[(size_t)(k0+nf*16+li)*DH + lg*8];
      half8 kb0 = *(const half8*)kr;
      half8 kb1 = *(const half8*)(kr + 32);
      #pragma unroll
      for (int mf=0;mf<2;mf++) {
        s[mf][nf] = __builtin_amdgcn_mfma_f32_16x16x32_f16(qf[mf][0], kb0, s[mf][nf],0,0,0);
        s[mf][nf] = __builtin_amdgcn_mfma_f32_16x16x32_f16(qf[mf][1], kb1, s[mf][nf],0,0,0);
      }
    }
    float rc[8];
    #pragma unroll
    for (int nf=0;nf<8;nf++) {
      int kk = k0 + nf*16 + li;
      rc[nf] = (mrow[kk] != 0.f) ? -1.f : 1.0f/csrow[kk];
    }
    // two passes over k-halves: repack 32x64 through LDS, then NT dwordx4 stores
    #pragma unroll
    for (int p=0;p<2;p++) {
      #pragma unroll
      for (int nf4=0;nf4<4;nf4++) {
        int nf = 4*p + nf4;
        #pragma unroll
        for (int mf=0;mf<2;mf++)
          #pragma unroll
          for (int r=0;r<4;r++) {
            float val = (rc[nf] < 0.f) ? UNIF
                                       : __expf(s[mf][nf][r]*0.125f)*rc[nf];
            Tw[(mf*16 + lg*4 + r)*68 + nf4*16 + li] = val;
          }
      }
      // wave-private tile: same-wave ds ordering (lgkmcnt) suffices, no barrier
      #pragma unroll
      for (int r4=0;r4<8;r4++) {
        int row = 4*r4 + lg;               // 4 q-rows per inst, 16 lanes x 16B each
        f32x4 v = *(const f32x4*)&Tw[row*68 + 4*li];
        __builtin_nontemporal_store(v,
            (f32x4*)(obase + (size_t)(q0+row)*SEQ + k0 + 64*p + 4*li));
      }
    }
  }
}

// ---------------------------------------------------------------- launch
extern "C" void kernel_launch(void* const* d_in, const int* in_sizes, int n_in,
                              void* d_out, int out_size, void* d_ws, size_t ws_size,
                              hipStream_t stream) {
  (void)in_sizes; (void)n_in; (void)out_size; (void)ws_size;
  const float* v_in = (const float*)d_in[0];
  const float* k_in = (const float*)d_in[1];
  const float* q_in = (const float*)d_in[2];
  const float* mask = (const float*)d_in[3];
  const float* wq_w = (const float*)d_in[5];
  const float* wq_b = (const float*)d_in[6];
  const float* wk_w = (const float*)d_in[7];
  const float* wk_b = (const float*)d_in[8];
  const float* wv_w = (const float*)d_in[9];
  const float* wv_b = (const float*)d_in[10];
  const float* wo_w = (const float*)d_in[11];
  const float* wo_b = (const float*)d_in[12];

  char* ws = (char*)d_ws;
  const size_t MB = 1024*1024;
  u16* xq  = (u16*)(ws);             // 8 MB each
  u16* xk  = (u16*)(ws + 8*MB);
  u16* xv  = (u16*)(ws + 16*MB);
  u16* wqt = (u16*)(ws + 24*MB);     // 2 MB each
  u16* wkt = (u16*)(ws + 26*MB);
  u16* wvt = (u16*)(ws + 28*MB);
  u16* wot = (u16*)(ws + 30*MB);
  u16* qh  = (u16*)(ws + 32*MB);     // 8 MB each
  u16* kh  = (u16*)(ws + 40*MB);
  u16* vt  = (u16*)(ws + 48*MB);
  u16* cc  = (u16*)(ws + 56*MB);
  float* colsum = (float*)(ws + 64*MB);  // 256 KB

  float* out0 = (float*)d_out;                       // (2,2048,1024)
  float* outw = out0 + (size_t)2*SEQ*DMODEL;         // (2,16,2048,2048)

  (void)hipMemsetAsync(colsum, 0, (size_t)32*SEQ*sizeof(float), stream);
  conv_qkv_k<<<dim3(2048,3), 256, 0, stream>>>(q_in, k_in, v_in, xq, xk, xv);
  conv_wt_k<<<dim3(16,16,4), 256, 0, stream>>>(wq_w, wk_w, wv_w, wo_w, wqt, wkt, wvt, wot);
  gemm16_k<0><<<dim3(32,16), 256, 0, stream>>>(xq, wqt, wq_b, qh);
  gemm16_k<0><<<dim3(32,16), 256, 0, stream>>>(xk, wkt, wk_b, kh);
  gemm16_k<1><<<dim3(32,16), 256, 0, stream>>>(xv, wvt, wv_b, vt);
  flash_k<<<dim3(32,32), 256, 0, stream>>>(qh, kh, vt, mask, cc, colsum);
  attnw_k<<<dim3(16,32,8), 256, 0, stream>>>(qh, kh, mask, colsum, outw);
  gemm16_k<2><<<dim3(32,16), 256, 0, stream>>>(cc, wot, wo_b, out0);
}

// Round 18
// 362.373 us; speedup vs baseline: 1.1288x; 1.0801x over previous
//
#include <hip/hip_runtime.h>

// MultiHeadAttention fwd, MI355X/gfx950.
// B=2, S=2048, D=1024, H=16, dh=64.
// d_out = [output (2*2048*1024 f32)] ++ [attn_weights = softmax(logits, axis=q) (2*16*2048*2048 f32)]
// R18 = R15 (384.3us best) with flash colsum de-atomicized: per-wave write-once
//       LDS slices (each wave visits each column exactly once) + epilogue 4-way sum.

typedef unsigned short u16;
typedef __attribute__((ext_vector_type(8))) short short8;
typedef __attribute__((ext_vector_type(8))) _Float16 half8;
typedef __attribute__((ext_vector_type(4))) float f32x4;

#define SEQ 2048
#define DMODEL 1024
#define NHEAD 16
#define DH 64

__device__ __forceinline__ u16 f2h(float f) {
  _Float16 h = (_Float16)f;
  return __builtin_bit_cast(u16, h);
}

// async global->LDS, 16B per lane; lds pointer must be wave-uniform (HW adds lane*16)
__device__ __forceinline__ void gload16(const void* g, void* l) {
  __builtin_amdgcn_global_load_lds(
      (__attribute__((address_space(1))) void*)const_cast<void*>(g),
      (__attribute__((address_space(3))) void*)l, 16, 0, 0);
}

// ---------------------------------------------------------------- converts
__global__ __launch_bounds__(256) void conv_qkv_k(
    const float* __restrict__ qs, const float* __restrict__ ks,
    const float* __restrict__ vs, u16* __restrict__ xq,
    u16* __restrict__ xk, u16* __restrict__ xv)
{
  int z = blockIdx.y;
  const float* s = (z == 0) ? qs : ((z == 1) ? ks : vs);
  u16* d = (z == 0) ? xq : ((z == 1) ? xk : xv);
  size_t i = ((size_t)blockIdx.x * 256 + threadIdx.x) * 8;
  float4 a = *(const float4*)(s + i);
  float4 b = *(const float4*)(s + i + 4);
  short8 o;
  o[0] = (short)f2h(a.x); o[1] = (short)f2h(a.y);
  o[2] = (short)f2h(a.z); o[3] = (short)f2h(a.w);
  o[4] = (short)f2h(b.x); o[5] = (short)f2h(b.y);
  o[6] = (short)f2h(b.z); o[7] = (short)f2h(b.w);
  *(short8*)(d + i) = o;
}

// W[k][n] f32 -> Wt[n][k] fp16 (so GEMM B-fragments read k-contiguous)
__global__ __launch_bounds__(256) void conv_wt_k(
    const float* __restrict__ w0, const float* __restrict__ w1,
    const float* __restrict__ w2, const float* __restrict__ w3,
    u16* __restrict__ t0, u16* __restrict__ t1,
    u16* __restrict__ t2, u16* __restrict__ t3)
{
  __shared__ u16 tile[64][65];
  int z = blockIdx.z;
  const float* W = (z==0)?w0:((z==1)?w1:((z==2)?w2:w3));
  u16* T = (z==0)?t0:((z==1)?t1:((z==2)?t2:t3));
  int k0 = blockIdx.x*64, n0 = blockIdx.y*64;
  int t = threadIdx.x;
  #pragma unroll
  for (int i=0;i<4;i++) {
    int idx = t + i*256;
    int r = idx >> 4, c4 = (idx & 15)*4;
    float4 f = *(const float4*)(W + (size_t)(k0+r)*DMODEL + n0 + c4);
    tile[r][c4+0] = f2h(f.x); tile[r][c4+1] = f2h(f.y);
    tile[r][c4+2] = f2h(f.z); tile[r][c4+3] = f2h(f.w);
  }
  __syncthreads();
  #pragma unroll
  for (int i=0;i<2;i++) {
    int idx = t + i*256;
    int nr = idx >> 3, c8 = (idx & 7)*8;
    short8 o;
    #pragma unroll
    for (int j=0;j<8;j++) o[j] = (short)tile[c8+j][nr];
    *(short8*)(T + (size_t)(n0+nr)*DMODEL + k0 + c8) = o;
  }
}

// ---------------------------------------------------------------- GEMM
// C[4096 x 1024] = A[4096 x 1024] @ Bt[1024 x 1024]^T + bias
// BM=128 BN=64 BK=64; 256 threads = 4 waves (2x2). 512 blocks (2/CU). ~12us each (R7).
template<int EPI>
__global__ __launch_bounds__(256) void gemm16_k(
    const u16* __restrict__ A, const u16* __restrict__ Bt,
    const float* __restrict__ bias, void* __restrict__ outp)
{
  __shared__ u16 As[128*64];   // 16 KB, chunk-swizzled c^(row&7)
  __shared__ u16 Bs[64*64];    // 8 KB
  const int K = 1024;
  int tid = threadIdx.x, w = tid>>6, l = tid&63;
  int m0 = blockIdx.x*128, n0 = blockIdx.y*64;
  int wm = (w>>1)*64, wn = (w&1)*32;
  const f32x4 z4 = {0.f,0.f,0.f,0.f};
  f32x4 acc[4][2];
  #pragma unroll
  for (int mf=0;mf<4;mf++)
    #pragma unroll
    for (int nf=0;nf<2;nf++) acc[mf][nf] = z4;

  for (int k0=0;k0<K;k0+=64) {
    #pragma unroll
    for (int i=0;i<4;i++) {  // A tile: 1024 chunks of 16B, 4 insts/wave
      int cd = (w*4+i)*64 + l, r = cd>>3, p = cd&7, c = p ^ (r&7);
      gload16(A + (size_t)(m0+r)*K + k0 + c*8, (char*)As + (w*4+i)*1024);
    }
    #pragma unroll
    for (int i=0;i<2;i++) {  // B tile: 512 chunks
      int cd = (w*2+i)*64 + l, r = cd>>3, p = cd&7, c = p ^ (r&7);
      gload16(Bt + (size_t)(n0+r)*K + k0 + c*8, (char*)Bs + (w*2+i)*1024);
    }
    __syncthreads();
    half8 a[4][2], b[2][2];
    #pragma unroll
    for (int mf=0;mf<4;mf++)
      #pragma unroll
      for (int kf=0;kf<2;kf++) {
        int row = wm + mf*16 + (l&15);
        int ch = (kf*4 + (l>>4)) ^ (row&7);
        a[mf][kf] = *(const half8*)&As[row*64 + ch*8];
      }
    #pragma unroll
    for (int nf=0;nf<2;nf++)
      #pragma unroll
      for (int kf=0;kf<2;kf++) {
        int row = wn + nf*16 + (l&15);
        int ch = (kf*4 + (l>>4)) ^ (row&7);
        b[nf][kf] = *(const half8*)&Bs[row*64 + ch*8];
      }
    #pragma unroll
    for (int kf=0;kf<2;kf++)
      #pragma unroll
      for (int mf=0;mf<4;mf++)
        #pragma unroll
        for (int nf=0;nf<2;nf++)
          acc[mf][nf] = __builtin_amdgcn_mfma_f32_16x16x32_f16(
              a[mf][kf], b[nf][kf], acc[mf][nf], 0,0,0);
    __syncthreads();
  }
  #pragma unroll
  for (int mf=0;mf<4;mf++)
    #pragma unroll
    for (int nf=0;nf<2;nf++)
      #pragma unroll
      for (int r=0;r<4;r++) {
        int m = m0 + wm + mf*16 + (l>>4)*4 + r;
        int n = n0 + wn + nf*16 + (l&15);
        float v = acc[mf][nf][r] + bias[n];
        if (EPI == 0) {
          int bb = m >> 11, s = m & 2047, hh = n >> 6, dd = n & 63;
          ((u16*)outp)[((size_t)((bb*16+hh)*2048 + s))*64 + dd] = f2h(v);
        } else if (EPI == 1) {
          int bb = m >> 11, s = m & 2047, hh = n >> 6, dd = n & 63;
          ((u16*)outp)[((size_t)((bb*16+hh)*64 + dd))*2048 + s] = f2h(v);
        } else {
          ((float*)outp)[(size_t)m*DMODEL + n] = v;
        }
      }
}

// ---------------------------------------------------------------- flash attention
// QBLK=64 (4 waves x 16 q-rows), grid (32,32)=1024 wg. KVBLK=128 per kt.
// K/V staged once per block into LDS via global_load_lds (pre-swizzled source),
// fragments via swizzled ds_read_b128.
// colsum: per-wave WRITE-ONCE slices (each wave visits each column exactly once;
// no atomics, no init) + epilogue 4-way sum + 1 global atomic per column.
// LDS: 16K(Ks)+16K(Vs)+16K(Ps)+32K(colbufW) = 80KB -> 2 blocks/CU.
__global__ __launch_bounds__(256) void flash_k(
    const u16* __restrict__ Qh, const u16* __restrict__ Kh,
    const u16* __restrict__ Vt, const float* __restrict__ mask,
    u16* __restrict__ Cc, float* __restrict__ colsum)
{
  __shared__ u16 Ks[128*64];      // 16 KB, chunk-swizzle c^(row&7)  (rows=k)
  __shared__ u16 Vs[64*128];      // 16 KB, chunk-swizzle c^(row&15) (rows=d)
  __shared__ u16 Ps[4][16*128];   // per-wave P staging
  __shared__ float colbufW[4][SEQ];  // 32 KB: per-wave write-once colsum slices
  int tid = threadIdx.x, w = tid>>6, l = tid&63;
  int lg = l>>4, li = l&15;
  int qb = blockIdx.x, bh = blockIdx.y, b = bh>>4, h = bh&15;
  const u16* Qb = Qh + (size_t)bh*SEQ*DH;
  const u16* Kb = Kh + (size_t)bh*SEQ*DH;
  const u16* Vb = Vt + (size_t)bh*DH*SEQ;
  const float* mrow = mask + (size_t)b*SEQ;
  int q0 = qb*64 + w*16;
  half8 qf[2];
  #pragma unroll
  for (int kf=0;kf<2;kf++)
    qf[kf] = *(const half8*)&Qb[(size_t)(q0+li)*DH + kf*32 + lg*8];
  const f32x4 z4 = {0.f,0.f,0.f,0.f};
  f32x4 acc[4];
  float lrow[4];
  #pragma unroll
  for (int df=0;df<4;df++) acc[df] = z4;
  #pragma unroll
  for (int r=0;r<4;r++) lrow[r] = 0.f;
  u16* Pw = &Ps[w][0];
  for (int kt=0;kt<16;kt++) {
    int k0 = kt*128;
    __syncthreads();   // previous tile's LDS reads complete before overwrite
    #pragma unroll
    for (int i=0;i<4;i++) {   // K tile: 1024 chunks of 16B
      int cd = (w*4+i)*64 + l, r = cd>>3, p = cd&7, c = p ^ (r&7);
      gload16(Kb + (size_t)(k0+r)*DH + c*8, (char*)Ks + (w*4+i)*1024);
    }
    #pragma unroll
    for (int i=0;i<4;i++) {   // V tile: 1024 chunks of 16B
      int cd = (w*4+i)*64 + l, r = cd>>4, p = cd&15, c = p ^ (r&15);
      gload16(Vb + (size_t)r*SEQ + k0 + c*8, (char*)Vs + (w*4+i)*1024);
    }
    __syncthreads();   // vmcnt drained before barrier -> tiles ready
    f32x4 s[8];
    #pragma unroll
    for (int nf=0;nf<8;nf++) s[nf] = z4;
    #pragma unroll
    for (int nf=0;nf<8;nf++) {
      int row = nf*16 + li;
      half8 kb0 = *(const half8*)&Ks[row*64 + ((lg    ) ^ (row&7))*8];
      half8 kb1 = *(const half8*)&Ks[row*64 + ((4 + lg) ^ (row&7))*8];
      s[nf] = __builtin_amdgcn_mfma_f32_16x16x32_f16(qf[0], kb0, s[nf],0,0,0);
      s[nf] = __builtin_amdgcn_mfma_f32_16x16x32_f16(qf[1], kb1, s[nf],0,0,0);
    }
    float mv[8], cp[8];
    #pragma unroll
    for (int nf=0;nf<8;nf++) {
      mv[nf] = mrow[k0 + nf*16 + li] * (-1e9f);
      cp[nf] = 0.f;
    }
    #pragma unroll
    for (int nf=0;nf<8;nf++) {
      f32x4 p;
      #pragma unroll
      for (int r=0;r<4;r++) {
        float e = __expf(s[nf][r]*0.125f + mv[nf]);
        e = fminf(e, 60000.f);   // fp16-range insurance
        p[r] = e;
        lrow[r] += e;
        cp[nf] += e;
      }
      s[nf] = p;
    }
    #pragma unroll
    for (int nf=0;nf<8;nf++) {     // column partials -> per-wave slice (write-once)
      float vsum = cp[nf];
      vsum += __shfl_xor(vsum, 16);
      vsum += __shfl_xor(vsum, 32);
      if (lg == 0) colbufW[w][k0 + nf*16 + li] = vsum;
    }
    // P (row=lg*4+r, col=li within nf) -> LDS transposed for PV A-operand
    #pragma unroll
    for (int nf=0;nf<8;nf++) {
      int kc = nf*16 + li;
      #pragma unroll
      for (int r=0;r<4;r++) {
        int row = lg*4 + r;
        int ch = (kc>>3) ^ row;
        Pw[row*128 + ch*8 + (kc&7)] = f2h(s[nf][r]);
      }
    }
    #pragma unroll
    for (int ks=0;ks<4;ks++) {
      half8 pa;
      {
        int row = li;
        int ch = (ks*4 + lg) ^ row;
        pa = *(const half8*)&Pw[row*128 + ch*8];
      }
      #pragma unroll
      for (int df=0;df<4;df++) {
        int vrow = df*16 + li;
        half8 vb = *(const half8*)&Vs[vrow*128 + ((ks*4 + lg) ^ (vrow&15))*8];
        acc[df] = __builtin_amdgcn_mfma_f32_16x16x32_f16(pa, vb, acc[df],0,0,0);
      }
    }
  }
  #pragma unroll
  for (int r=0;r<4;r++) {        // finalize row sums over the 16 col-lanes
    float vsum = lrow[r];
    vsum += __shfl_xor(vsum, 1);
    vsum += __shfl_xor(vsum, 2);
    vsum += __shfl_xor(vsum, 4);
    vsum += __shfl_xor(vsum, 8);
    lrow[r] = 1.0f / vsum;
  }
  #pragma unroll
  for (int df=0;df<4;df++)
    #pragma unroll
    for (int r=0;r<4;r++) {
      int qrow = q0 + lg*4 + r;
      int col = h*64 + df*16 + li;
      Cc[(size_t)(b*SEQ + qrow)*DMODEL + col] = f2h(acc[df][r] * lrow[r]);
    }
  __syncthreads();   // all slices written
  for (int i=tid;i<SEQ;i+=256) {
    float v = (colbufW[0][i] + colbufW[1][i]) + (colbufW[2][i] + colbufW[3][i]);
    atomicAdd(&colsum[(size_t)bh*SEQ + i], v);
  }
}

// ---------------------------------------------------------------- attn_weights write pass
// Per-wave LDS repack (32x64 f32 tile, stride-68 pad) -> NT dwordx4 stores (R15 best).
__global__ __launch_bounds__(256) void attnw_k(
    const u16* __restrict__ Qh, const u16* __restrict__ Kh,
    const float* __restrict__ mask, const float* __restrict__ colsum,
    float* __restrict__ outw)
{
  __shared__ float Ts[4][32*68];   // 34 KB: per-wave private repack tile
  int tid = threadIdx.x, w = tid>>6, l = tid&63;
  int lg = l>>4, li = l&15;
  int qb = blockIdx.x, bh = blockIdx.y, b = bh>>4;
  int kseg = blockIdx.z;
  const u16* Qb = Qh + (size_t)bh*SEQ*DH;
  const u16* Kb = Kh + (size_t)bh*SEQ*DH;
  const float* mrow = mask + (size_t)b*SEQ;
  const float* csrow = colsum + (size_t)bh*SEQ;
  float* obase = outw + (size_t)bh*SEQ*SEQ;
  int q0 = qb*128 + w*32;
  half8 qf[2][2];
  #pragma unroll
  for (int mf=0;mf<2;mf++)
    #pragma unroll
    for (int kf=0;kf<2;kf++)
      qf[mf][kf] = *(const half8*)&Qb[(size_t)(q0+mf*16+li)*DH + kf*32 + lg*8];
  const f32x4 z4 = {0.f,0.f,0.f,0.f};
  const float UNIF = 4.8828125e-4f;   // 1/2048
  float* Tw = &Ts[w][0];
  for (int kt=kseg*2;kt<kseg*2+2;kt++) {
    int k0 = kt*128;
    f32x4 s[2][8];
    #pragma unroll
    for (int mf=0;mf<2;mf++)
      #pragma unroll
      for (int nf=0;nf<8;nf++) s[mf][nf] = z4;
    #pragma unroll
    for (int nf=0;nf<8;nf++) {
      const u16* kr = &Kb[(size_t)(k0+nf*16+li)*DH + lg*8];
      half8 kb0 = *(const half8*)kr;
      half8 kb1 = *(const half8*)(kr + 32);
      #pragma unroll
      for (int mf=0;mf<2;mf++) {
        s[mf][nf] = __builtin_amdgcn_mfma_f32_16x16x32_f16(qf[mf][0], kb0, s[mf][nf],0,0,0);
        s[mf][nf] = __builtin_amdgcn_mfma_f32_16x16x32_f16(qf[mf][1], kb1, s[mf][nf],0,0,0);
      }
    }
    float rc[8];
    #pragma unroll
    for (int nf=0;nf<8;nf++) {
      int kk = k0 + nf*16 + li;
      rc[nf] = (mrow[kk] != 0.f) ? -1.f : 1.0f/csrow[kk];
    }
    // two passes over k-halves: repack 32x64 through LDS, then NT dwordx4 stores
    #pragma unroll
    for (int p=0;p<2;p++) {
      #pragma unroll
      for (int nf4=0;nf4<4;nf4++) {
        int nf = 4*p + nf4;
        #pragma unroll
        for (int mf=0;mf<2;mf++)
          #pragma unroll
          for (int r=0;r<4;r++) {
            float val = (rc[nf] < 0.f) ? UNIF
                                       : __expf(s[mf][nf][r]*0.125f)*rc[nf];
            Tw[(mf*16 + lg*4 + r)*68 + nf4*16 + li] = val;
          }
      }
      // wave-private tile: same-wave ds ordering (lgkmcnt) suffices, no barrier
      #pragma unroll
      for (int r4=0;r4<8;r4++) {
        int row = 4*r4 + lg;               // 4 q-rows per inst, 16 lanes x 16B each
        f32x4 v = *(const f32x4*)&Tw[row*68 + 4*li];
        __builtin_nontemporal_store(v,
            (f32x4*)(obase + (size_t)(q0+row)*SEQ + k0 + 64*p + 4*li));
      }
    }
  }
}

// ---------------------------------------------------------------- launch
extern "C" void kernel_launch(void* const* d_in, const int* in_sizes, int n_in,
                              void* d_out, int out_size, void* d_ws, size_t ws_size,
                              hipStream_t stream) {
  (void)in_sizes; (void)n_in; (void)out_size; (void)ws_size;
  const float* v_in = (const float*)d_in[0];
  const float* k_in = (const float*)d_in[1];
  const float* q_in = (const float*)d_in[2];
  const float* mask = (const float*)d_in[3];
  const float* wq_w = (const float*)d_in[5];
  const float* wq_b = (const float*)d_in[6];
  const float* wk_w = (const float*)d_in[7];
  const float* wk_b = (const float*)d_in[8];
  const float* wv_w = (const float*)d_in[9];
  const float* wv_b = (const float*)d_in[10];
  const float* wo_w = (const float*)d_in[11];
  const float* wo_b = (const float*)d_in[12];

  char* ws = (char*)d_ws;
  const size_t MB = 1024*1024;
  u16* xq  = (u16*)(ws);             // 8 MB each
  u16* xk  = (u16*)(ws + 8*MB);
  u16* xv  = (u16*)(ws + 16*MB);
  u16* wqt = (u16*)(ws + 24*MB);     // 2 MB each
  u16* wkt = (u16*)(ws + 26*MB);
  u16* wvt = (u16*)(ws + 28*MB);
  u16* wot = (u16*)(ws + 30*MB);
  u16* qh  = (u16*)(ws + 32*MB);     // 8 MB each
  u16* kh  = (u16*)(ws + 40*MB);
  u16* vt  = (u16*)(ws + 48*MB);
  u16* cc  = (u16*)(ws + 56*MB);
  float* colsum = (float*)(ws + 64*MB);  // 256 KB

  float* out0 = (float*)d_out;                       // (2,2048,1024)
  float* outw = out0 + (size_t)2*SEQ*DMODEL;         // (2,16,2048,2048)

  (void)hipMemsetAsync(colsum, 0, (size_t)32*SEQ*sizeof(float), stream);
  conv_qkv_k<<<dim3(2048,3), 256, 0, stream>>>(q_in, k_in, v_in, xq, xk, xv);
  conv_wt_k<<<dim3(16,16,4), 256, 0, stream>>>(wq_w, wk_w, wv_w, wo_w, wqt, wkt, wvt, wot);
  gemm16_k<0><<<dim3(32,16), 256, 0, stream>>>(xq, wqt, wq_b, qh);
  gemm16_k<0><<<dim3(32,16), 256, 0, stream>>>(xk, wkt, wk_b, kh);
  gemm16_k<1><<<dim3(32,16), 256, 0, stream>>>(xv, wvt, wv_b, vt);
  flash_k<<<dim3(32,32), 256, 0, stream>>>(qh, kh, vt, mask, cc, colsum);
  attnw_k<<<dim3(16,32,8), 256, 0, stream>>>(qh, kh, mask, colsum, outw);
  gemm16_k<2><<<dim3(32,16), 256, 0, stream>>>(cc, wot, wo_b, out0);
}

// Round 20
// 359.507 us; speedup vs baseline: 1.1378x; 1.0080x over previous
//
#include <hip/hip_runtime.h>

// MultiHeadAttention fwd, MI355X/gfx950.
// B=2, S=2048, D=1024, H=16, dh=64.
// d_out = [output (2*2048*1024 f32)] ++ [attn_weights = softmax(logits, axis=q) (2*16*2048*2048 f32)]
// R20 = R18 verbatim (362.4us verified best). R19's tr_read experiment failed correctness
//       (2nd failed tr_read derivation) -> pre-declared revert.

typedef unsigned short u16;
typedef __attribute__((ext_vector_type(8))) short short8;
typedef __attribute__((ext_vector_type(8))) _Float16 half8;
typedef __attribute__((ext_vector_type(4))) float f32x4;

#define SEQ 2048
#define DMODEL 1024
#define NHEAD 16
#define DH 64

__device__ __forceinline__ u16 f2h(float f) {
  _Float16 h = (_Float16)f;
  return __builtin_bit_cast(u16, h);
}

// async global->LDS, 16B per lane; lds pointer must be wave-uniform (HW adds lane*16)
__device__ __forceinline__ void gload16(const void* g, void* l) {
  __builtin_amdgcn_global_load_lds(
      (__attribute__((address_space(1))) void*)const_cast<void*>(g),
      (__attribute__((address_space(3))) void*)l, 16, 0, 0);
}

// ---------------------------------------------------------------- converts
__global__ __launch_bounds__(256) void conv_qkv_k(
    const float* __restrict__ qs, const float* __restrict__ ks,
    const float* __restrict__ vs, u16* __restrict__ xq,
    u16* __restrict__ xk, u16* __restrict__ xv)
{
  int z = blockIdx.y;
  const float* s = (z == 0) ? qs : ((z == 1) ? ks : vs);
  u16* d = (z == 0) ? xq : ((z == 1) ? xk : xv);
  size_t i = ((size_t)blockIdx.x * 256 + threadIdx.x) * 8;
  float4 a = *(const float4*)(s + i);
  float4 b = *(const float4*)(s + i + 4);
  short8 o;
  o[0] = (short)f2h(a.x); o[1] = (short)f2h(a.y);
  o[2] = (short)f2h(a.z); o[3] = (short)f2h(a.w);
  o[4] = (short)f2h(b.x); o[5] = (short)f2h(b.y);
  o[6] = (short)f2h(b.z); o[7] = (short)f2h(b.w);
  *(short8*)(d + i) = o;
}

// W[k][n] f32 -> Wt[n][k] fp16 (so GEMM B-fragments read k-contiguous)
__global__ __launch_bounds__(256) void conv_wt_k(
    const float* __restrict__ w0, const float* __restrict__ w1,
    const float* __restrict__ w2, const float* __restrict__ w3,
    u16* __restrict__ t0, u16* __restrict__ t1,
    u16* __restrict__ t2, u16* __restrict__ t3)
{
  __shared__ u16 tile[64][65];
  int z = blockIdx.z;
  const float* W = (z==0)?w0:((z==1)?w1:((z==2)?w2:w3));
  u16* T = (z==0)?t0:((z==1)?t1:((z==2)?t2:t3));
  int k0 = blockIdx.x*64, n0 = blockIdx.y*64;
  int t = threadIdx.x;
  #pragma unroll
  for (int i=0;i<4;i++) {
    int idx = t + i*256;
    int r = idx >> 4, c4 = (idx & 15)*4;
    float4 f = *(const float4*)(W + (size_t)(k0+r)*DMODEL + n0 + c4);
    tile[r][c4+0] = f2h(f.x); tile[r][c4+1] = f2h(f.y);
    tile[r][c4+2] = f2h(f.z); tile[r][c4+3] = f2h(f.w);
  }
  __syncthreads();
  #pragma unroll
  for (int i=0;i<2;i++) {
    int idx = t + i*256;
    int nr = idx >> 3, c8 = (idx & 7)*8;
    short8 o;
    #pragma unroll
    for (int j=0;j<8;j++) o[j] = (short)tile[c8+j][nr];
    *(short8*)(T + (size_t)(n0+nr)*DMODEL + k0 + c8) = o;
  }
}

// ---------------------------------------------------------------- GEMM
// C[4096 x 1024] = A[4096 x 1024] @ Bt[1024 x 1024]^T + bias
// BM=128 BN=64 BK=64; 256 threads = 4 waves (2x2). 512 blocks (2/CU). ~12us each (R7).
template<int EPI>
__global__ __launch_bounds__(256) void gemm16_k(
    const u16* __restrict__ A, const u16* __restrict__ Bt,
    const float* __restrict__ bias, void* __restrict__ outp)
{
  __shared__ u16 As[128*64];   // 16 KB, chunk-swizzled c^(row&7)
  __shared__ u16 Bs[64*64];    // 8 KB
  const int K = 1024;
  int tid = threadIdx.x, w = tid>>6, l = tid&63;
  int m0 = blockIdx.x*128, n0 = blockIdx.y*64;
  int wm = (w>>1)*64, wn = (w&1)*32;
  const f32x4 z4 = {0.f,0.f,0.f,0.f};
  f32x4 acc[4][2];
  #pragma unroll
  for (int mf=0;mf<4;mf++)
    #pragma unroll
    for (int nf=0;nf<2;nf++) acc[mf][nf] = z4;

  for (int k0=0;k0<K;k0+=64) {
    #pragma unroll
    for (int i=0;i<4;i++) {  // A tile: 1024 chunks of 16B, 4 insts/wave
      int cd = (w*4+i)*64 + l, r = cd>>3, p = cd&7, c = p ^ (r&7);
      gload16(A + (size_t)(m0+r)*K + k0 + c*8, (char*)As + (w*4+i)*1024);
    }
    #pragma unroll
    for (int i=0;i<2;i++) {  // B tile: 512 chunks
      int cd = (w*2+i)*64 + l, r = cd>>3, p = cd&7, c = p ^ (r&7);
      gload16(Bt + (size_t)(n0+r)*K + k0 + c*8, (char*)Bs + (w*2+i)*1024);
    }
    __syncthreads();
    half8 a[4][2], b[2][2];
    #pragma unroll
    for (int mf=0;mf<4;mf++)
      #pragma unroll
      for (int kf=0;kf<2;kf++) {
        int row = wm + mf*16 + (l&15);
        int ch = (kf*4 + (l>>4)) ^ (row&7);
        a[mf][kf] = *(const half8*)&As[row*64 + ch*8];
      }
    #pragma unroll
    for (int nf=0;nf<2;nf++)
      #pragma unroll
      for (int kf=0;kf<2;kf++) {
        int row = wn + nf*16 + (l&15);
        int ch = (kf*4 + (l>>4)) ^ (row&7);
        b[nf][kf] = *(const half8*)&Bs[row*64 + ch*8];
      }
    #pragma unroll
    for (int kf=0;kf<2;kf++)
      #pragma unroll
      for (int mf=0;mf<4;mf++)
        #pragma unroll
        for (int nf=0;nf<2;nf++)
          acc[mf][nf] = __builtin_amdgcn_mfma_f32_16x16x32_f16(
              a[mf][kf], b[nf][kf], acc[mf][nf], 0,0,0);
    __syncthreads();
  }
  #pragma unroll
  for (int mf=0;mf<4;mf++)
    #pragma unroll
    for (int nf=0;nf<2;nf++)
      #pragma unroll
      for (int r=0;r<4;r++) {
        int m = m0 + wm + mf*16 + (l>>4)*4 + r;
        int n = n0 + wn + nf*16 + (l&15);
        float v = acc[mf][nf][r] + bias[n];
        if (EPI == 0) {
          int bb = m >> 11, s = m & 2047, hh = n >> 6, dd = n & 63;
          ((u16*)outp)[((size_t)((bb*16+hh)*2048 + s))*64 + dd] = f2h(v);
        } else if (EPI == 1) {
          int bb = m >> 11, s = m & 2047, hh = n >> 6, dd = n & 63;
          ((u16*)outp)[((size_t)((bb*16+hh)*64 + dd))*2048 + s] = f2h(v);
        } else {
          ((float*)outp)[(size_t)m*DMODEL + n] = v;
        }
      }
}

// ---------------------------------------------------------------- flash attention
// QBLK=64 (4 waves x 16 q-rows), grid (32,32)=1024 wg. KVBLK=128 per kt.
// K/V staged once per block into LDS via global_load_lds (pre-swizzled source),
// fragments via swizzled ds_read_b128.
// colsum: per-wave WRITE-ONCE slices (no atomics) + epilogue 4-way sum (R18 win).
// LDS: 16K(Ks)+16K(Vs)+16K(Ps)+32K(colbufW) = 80KB -> 2 blocks/CU.
__global__ __launch_bounds__(256) void flash_k(
    const u16* __restrict__ Qh, const u16* __restrict__ Kh,
    const u16* __restrict__ Vt, const float* __restrict__ mask,
    u16* __restrict__ Cc, float* __restrict__ colsum)
{
  __shared__ u16 Ks[128*64];      // 16 KB, chunk-swizzle c^(row&7)  (rows=k)
  __shared__ u16 Vs[64*128];      // 16 KB, chunk-swizzle c^(row&15) (rows=d)
  __shared__ u16 Ps[4][16*128];   // per-wave P staging
  __shared__ float colbufW[4][SEQ];  // 32 KB: per-wave write-once colsum slices
  int tid = threadIdx.x, w = tid>>6, l = tid&63;
  int lg = l>>4, li = l&15;
  int qb = blockIdx.x, bh = blockIdx.y, b = bh>>4, h = bh&15;
  const u16* Qb = Qh + (size_t)bh*SEQ*DH;
  const u16* Kb = Kh + (size_t)bh*SEQ*DH;
  const u16* Vb = Vt + (size_t)bh*DH*SEQ;
  const float* mrow = mask + (size_t)b*SEQ;
  int q0 = qb*64 + w*16;
  half8 qf[2];
  #pragma unroll
  for (int kf=0;kf<2;kf++)
    qf[kf] = *(const half8*)&Qb[(size_t)(q0+li)*DH + kf*32 + lg*8];
  const f32x4 z4 = {0.f,0.f,0.f,0.f};
  f32x4 acc[4];
  float lrow[4];
  #pragma unroll
  for (int df=0;df<4;df++) acc[df] = z4;
  #pragma unroll
  for (int r=0;r<4;r++) lrow[r] = 0.f;
  u16* Pw = &Ps[w][0];
  for (int kt=0;kt<16;kt++) {
    int k0 = kt*128;
    __syncthreads();   // previous tile's LDS reads complete before overwrite
    #pragma unroll
    for (int i=0;i<4;i++) {   // K tile: 1024 chunks of 16B
      int cd = (w*4+i)*64 + l, r = cd>>3, p = cd&7, c = p ^ (r&7);
      gload16(Kb + (size_t)(k0+r)*DH + c*8, (char*)Ks + (w*4+i)*1024);
    }
    #pragma unroll
    for (int i=0;i<4;i++) {   // V tile: 1024 chunks of 16B
      int cd = (w*4+i)*64 + l, r = cd>>4, p = cd&15, c = p ^ (r&15);
      gload16(Vb + (size_t)r*SEQ + k0 + c*8, (char*)Vs + (w*4+i)*1024);
    }
    __syncthreads();   // vmcnt drained before barrier -> tiles ready
    f32x4 s[8];
    #pragma unroll
    for (int nf=0;nf<8;nf++) s[nf] = z4;
    #pragma unroll
    for (int nf=0;nf<8;nf++) {
      int row = nf*16 + li;
      half8 kb0 = *(const half8*)&Ks[row*64 + ((lg    ) ^ (row&7))*8];
      half8 kb1 = *(const half8*)&Ks[row*64 + ((4 + lg) ^ (row&7))*8];
      s[nf] = __builtin_amdgcn_mfma_f32_16x16x32_f16(qf[0], kb0, s[nf],0,0,0);
      s[nf] = __builtin_amdgcn_mfma_f32_16x16x32_f16(qf[1], kb1, s[nf],0,0,0);
    }
    float mv[8], cp[8];
    #pragma unroll
    for (int nf=0;nf<8;nf++) {
      mv[nf] = mrow[k0 + nf*16 + li] * (-1e9f);
      cp[nf] = 0.f;
    }
    #pragma unroll
    for (int nf=0;nf<8;nf++) {
      f32x4 p;
      #pragma unroll
      for (int r=0;r<4;r++) {
        float e = __expf(s[nf][r]*0.125f + mv[nf]);
        e = fminf(e, 60000.f);   // fp16-range insurance
        p[r] = e;
        lrow[r] += e;
        cp[nf] += e;
      }
      s[nf] = p;
    }
    #pragma unroll
    for (int nf=0;nf<8;nf++) {     // column partials -> per-wave slice (write-once)
      float vsum = cp[nf];
      vsum += __shfl_xor(vsum, 16);
      vsum += __shfl_xor(vsum, 32);
      if (lg == 0) colbufW[w][k0 + nf*16 + li] = vsum;
    }
    // P (row=lg*4+r, col=li within nf) -> LDS transposed for PV A-operand
    #pragma unroll
    for (int nf=0;nf<8;nf++) {
      int kc = nf*16 + li;
      #pragma unroll
      for (int r=0;r<4;r++) {
        int row = lg*4 + r;
        int ch = (kc>>3) ^ row;
        Pw[row*128 + ch*8 + (kc&7)] = f2h(s[nf][r]);
      }
    }
    #pragma unroll
    for (int ks=0;ks<4;ks++) {
      half8 pa;
      {
        int row = li;
        int ch = (ks*4 + lg) ^ row;
        pa = *(const half8*)&Pw[row*128 + ch*8];
      }
      #pragma unroll
      for (int df=0;df<4;df++) {
        int vrow = df*16 + li;
        half8 vb = *(const half8*)&Vs[vrow*128 + ((ks*4 + lg) ^ (vrow&15))*8];
        acc[df] = __builtin_amdgcn_mfma_f32_16x16x32_f16(pa, vb, acc[df],0,0,0);
      }
    }
  }
  #pragma unroll
  for (int r=0;r<4;r++) {        // finalize row sums over the 16 col-lanes
    float vsum = lrow[r];
    vsum += __shfl_xor(vsum, 1);
    vsum += __shfl_xor(vsum, 2);
    vsum += __shfl_xor(vsum, 4);
    vsum += __shfl_xor(vsum, 8);
    lrow[r] = 1.0f / vsum;
  }
  #pragma unroll
  for (int df=0;df<4;df++)
    #pragma unroll
    for (int r=0;r<4;r++) {
      int qrow = q0 + lg*4 + r;
      int col = h*64 + df*16 + li;
      Cc[(size_t)(b*SEQ + qrow)*DMODEL + col] = f2h(acc[df][r] * lrow[r]);
    }
  __syncthreads();   // all slices written
  for (int i=tid;i<SEQ;i+=256) {
    float v = (colbufW[0][i] + colbufW[1][i]) + (colbufW[2][i] + colbufW[3][i]);
    atomicAdd(&colsum[(size_t)bh*SEQ + i], v);
  }
}

// ---------------------------------------------------------------- attn_weights write pass
// Per-wave LDS repack (32x64 f32 tile, stride-68 pad) -> NT dwordx4 stores (R15 best).
__global__ __launch_bounds__(256) void attnw_k(
    const u16* __restrict__ Qh, const u16* __restrict__ Kh,
    const float* __restrict__ mask, const float* __restrict__ colsum,
    float* __restrict__ outw)
{
  __shared__ float Ts[4][32*68];   // 34 KB: per-wave private repack tile
  int tid = threadIdx.x, w = tid>>6, l = tid&63;
  int lg = l>>4, li = l&15;
  int qb = blockIdx.x, bh = blockIdx.y, b = bh>>4;
  int kseg = blockIdx.z;
  const u16* Qb = Qh + (size_t)bh*SEQ*DH;
  const u16* Kb = Kh + (size_t)bh*SEQ*DH;
  const float* mrow = mask + (size_t)b*SEQ;
  const float* csrow = colsum + (size_t)bh*SEQ;
  float* obase = outw + (size_t)bh*SEQ*SEQ;
  int q0 = qb*128 + w*32;
  half8 qf[2][2];
  #pragma unroll
  for (int mf=0;mf<2;mf++)
    #pragma unroll
    for (int kf=0;kf<2;kf++)
      qf[mf][kf] = *(const half8*)&Qb[(size_t)(q0+mf*16+li)*DH + kf*32 + lg*8];
  const f32x4 z4 = {0.f,0.f,0.f,0.f};
  const float UNIF = 4.8828125e-4f;   // 1/2048
  float* Tw = &Ts[w][0];
  for (int kt=kseg*2;kt<kseg*2+2;kt++) {
    int k0 = kt*128;
    f32x4 s[2][8];
    #pragma unroll
    for (int mf=0;mf<2;mf++)
      #pragma unroll
      for (int nf=0;nf<8;nf++) s[mf][nf] = z4;
    #pragma unroll
    for (int nf=0;nf<8;nf++) {
      const u16* kr = &Kb[(size_t)(k0+nf*16+li)*DH + lg*8];
      half8 kb0 = *(const half8*)kr;
      half8 kb1 = *(const half8*)(kr + 32);
      #pragma unroll
      for (int mf=0;mf<2;mf++) {
        s[mf][nf] = __builtin_amdgcn_mfma_f32_16x16x32_f16(qf[mf][0], kb0, s[mf][nf],0,0,0);
        s[mf][nf] = __builtin_amdgcn_mfma_f32_16x16x32_f16(qf[mf][1], kb1, s[mf][nf],0,0,0);
      }
    }
    float rc[8];
    #pragma unroll
    for (int nf=0;nf<8;nf++) {
      int kk = k0 + nf*16 + li;
      rc[nf] = (mrow[kk] != 0.f) ? -1.f : 1.0f/csrow[kk];
    }
    // two passes over k-halves: repack 32x64 through LDS, then NT dwordx4 stores
    #pragma unroll
    for (int p=0;p<2;p++) {
      #pragma unroll
      for (int nf4=0;nf4<4;nf4++) {
        int nf = 4*p + nf4;
        #pragma unroll
        for (int mf=0;mf<2;mf++)
          #pragma unroll
          for (int r=0;r<4;r++) {
            float val = (rc[nf] < 0.f) ? UNIF
                                       : __expf(s[mf][nf][r]*0.125f)*rc[nf];
            Tw[(mf*16 + lg*4 + r)*68 + nf4*16 + li] = val;
          }
      }
      // wave-private tile: same-wave ds ordering (lgkmcnt) suffices, no barrier
      #pragma unroll
      for (int r4=0;r4<8;r4++) {
        int row = 4*r4 + lg;               // 4 q-rows per inst, 16 lanes x 16B each
        f32x4 v = *(const f32x4*)&Tw[row*68 + 4*li];
        __builtin_nontemporal_store(v,
            (f32x4*)(obase + (size_t)(q0+row)*SEQ + k0 + 64*p + 4*li));
      }
    }
  }
}

// ---------------------------------------------------------------- launch
extern "C" void kernel_launch(void* const* d_in, const int* in_sizes, int n_in,
                              void* d_out, int out_size, void* d_ws, size_t ws_size,
                              hipStream_t stream) {
  (void)in_sizes; (void)n_in; (void)out_size; (void)ws_size;
  const float* v_in = (const float*)d_in[0];
  const float* k_in = (const float*)d_in[1];
  const float* q_in = (const float*)d_in[2];
  const float* mask = (const float*)d_in[3];
  const float* wq_w = (const float*)d_in[5];
  const float* wq_b = (const float*)d_in[6];
  const float* wk_w = (const float*)d_in[7];
  const float* wk_b = (const float*)d_in[8];
  const float* wv_w = (const float*)d_in[9];
  const float* wv_b = (const float*)d_in[10];
  const float* wo_w = (const float*)d_in[11];
  const float* wo_b = (const float*)d_in[12];

  char* ws = (char*)d_ws;
  const size_t MB = 1024*1024;
  u16* xq  = (u16*)(ws);             // 8 MB each
  u16* xk  = (u16*)(ws + 8*MB);
  u16* xv  = (u16*)(ws + 16*MB);
  u16* wqt = (u16*)(ws + 24*MB);     // 2 MB each
  u16* wkt = (u16*)(ws + 26*MB);
  u16* wvt = (u16*)(ws + 28*MB);
  u16* wot = (u16*)(ws + 30*MB);
  u16* qh  = (u16*)(ws + 32*MB);     // 8 MB each
  u16* kh  = (u16*)(ws + 40*MB);
  u16* vt  = (u16*)(ws + 48*MB);
  u16* cc  = (u16*)(ws + 56*MB);
  float* colsum = (float*)(ws + 64*MB);  // 256 KB

  float* out0 = (float*)d_out;                       // (2,2048,1024)
  float* outw = out0 + (size_t)2*SEQ*DMODEL;         // (2,16,2048,2048)

  (void)hipMemsetAsync(colsum, 0, (size_t)32*SEQ*sizeof(float), stream);
  conv_qkv_k<<<dim3(2048,3), 256, 0, stream>>>(q_in, k_in, v_in, xq, xk, xv);
  conv_wt_k<<<dim3(16,16,4), 256, 0, stream>>>(wq_w, wk_w, wv_w, wo_w, wqt, wkt, wvt, wot);
  gemm16_k<0><<<dim3(32,16), 256, 0, stream>>>(xq, wqt, wq_b, qh);
  gemm16_k<0><<<dim3(32,16), 256, 0, stream>>>(xk, wkt, wk_b, kh);
  gemm16_k<1><<<dim3(32,16), 256, 0, stream>>>(xv, wvt, wv_b, vt);
  flash_k<<<dim3(32,32), 256, 0, stream>>>(qh, kh, vt, mask, cc, colsum);
  attnw_k<<<dim3(16,32,8), 256, 0, stream>>>(qh, kh, mask, colsum, outw);
  gemm16_k<2><<<dim3(32,16), 256, 0, stream>>>(cc, wot, wo_b, out0);
}